// Round 6
// baseline (188.166 us; speedup 1.0000x reference)
//
#include <hip/hip_runtime.h>
#include <limits.h>
#include <math.h>

// Problem constants (fixed by setup_inputs)
#define VOCAB 50257
#define BSZ 64
#define BEAM 8
#define NG 4
#define NSTEP 5
#define BLK 256
#define NB 4                               // blocks per beam-row
#define CHA ((VOCAB + NB - 1) / NB)        // 12565 elements per block
#define NROWS (BSZ * BEAM)                 // 512
#define NBLKS (NROWS * NB)                 // 2048
#define CAP 1024                           // per-row filtered-candidate capacity

struct Cand { float v; int i; };

// ---------------- value-only sorted-8 primitives (threshold pass) ----------
#define CEV(a, b) do { float _t = fmaxf(a, b); b = fminf(a, b); a = _t; } while (0)
#define SORT8V() do { \
    CEV(w0,w4); CEV(w1,w5); CEV(w2,w6); CEV(w3,w7); \
    CEV(w0,w2); CEV(w1,w3); CEV(w4,w6); CEV(w5,w7); \
    CEV(w0,w1); CEV(w2,w3); CEV(w4,w5); CEV(w6,w7); } while (0)
#define XMERGEV(OFF) do { \
    float p0=__shfl_xor(w0,OFF), p1=__shfl_xor(w1,OFF), p2=__shfl_xor(w2,OFF), p3=__shfl_xor(w3,OFF); \
    float p4=__shfl_xor(w4,OFF), p5=__shfl_xor(w5,OFF), p6=__shfl_xor(w6,OFF), p7=__shfl_xor(w7,OFF); \
    w0=fmaxf(w0,p7); w1=fmaxf(w1,p6); w2=fmaxf(w2,p5); w3=fmaxf(w3,p4); \
    w4=fmaxf(w4,p3); w5=fmaxf(w5,p2); w6=fmaxf(w6,p1); w7=fmaxf(w7,p0); \
    SORT8V(); } while (0)
#define INSV(T) do { float _t = (T); if (_t > w7) { w7 = _t; \
    CEV(w6,w7); CEV(w5,w6); CEV(w4,w5); CEV(w3,w4); CEV(w2,w3); CEV(w1,w2); CEV(w0,w1); } } while (0)

// ---------------- (value, index) exact primitives (tiny final pass) --------
__device__ __forceinline__ bool pref(float av, int ai, float bv, int bi) {
    return (av > bv) || (av == bv && ai < bi);   // lax.top_k tie-break
}
__device__ __forceinline__ void ce(float& a, int& ia, float& b, int& ib) {
    if (pref(b, ib, a, ia)) { float tv = a; int ti = ia; a = b; ia = ib; b = tv; ib = ti; }
}
__device__ __forceinline__ void hc(float& a, int& ia, float b, int ib) {
    if (pref(b, ib, a, ia)) { a = b; ia = ib; }
}
__device__ __forceinline__ void merge2(float& v0, int& i0, float& v1, int& i1,
                                       float bv0, int bi0, float bv1, int bi1) {
    if (pref(bv0, bi0, v0, i0)) {
        float nv1; int ni1;
        if (pref(v0, i0, bv1, bi1)) { nv1 = v0; ni1 = i0; } else { nv1 = bv1; ni1 = bi1; }
        v0 = bv0; i0 = bi0; v1 = nv1; i1 = ni1;
    } else if (pref(bv0, bi0, v1, i1)) {
        v1 = bv0; i1 = bi0;
    }
}
#define SORT8P() do { \
    ce(v0,i0,v4,i4); ce(v1,i1,v5,i5); ce(v2,i2,v6,i6); ce(v3,i3,v7,i7); \
    ce(v0,i0,v2,i2); ce(v1,i1,v3,i3); ce(v4,i4,v6,i6); ce(v5,i5,v7,i7); \
    ce(v0,i0,v1,i1); ce(v2,i2,v3,i3); ce(v4,i4,v5,i5); ce(v6,i6,v7,i7); } while (0)
#define INSP(T, FI) do { float _t = (T); int _f = (FI); \
    if (pref(_t, _f, v7, i7)) { v7 = _t; i7 = _f; \
        ce(v6,i6,v7,i7); ce(v5,i5,v6,i6); ce(v4,i4,v5,i5); ce(v3,i3,v4,i4); \
        ce(v2,i2,v3,i3); ce(v1,i1,v2,i2); ce(v0,i0,v1,i1); } } while (0)
#define XMERGEP(OFF) do { \
    float pv0=__shfl_xor(v0,OFF), pv1=__shfl_xor(v1,OFF), pv2=__shfl_xor(v2,OFF), pv3=__shfl_xor(v3,OFF); \
    float pv4=__shfl_xor(v4,OFF), pv5=__shfl_xor(v5,OFF), pv6=__shfl_xor(v6,OFF), pv7=__shfl_xor(v7,OFF); \
    int   pi0=__shfl_xor(i0,OFF), pi1=__shfl_xor(i1,OFF), pi2=__shfl_xor(i2,OFF), pi3=__shfl_xor(i3,OFF); \
    int   pi4=__shfl_xor(i4,OFF), pi5=__shfl_xor(i5,OFF), pi6=__shfl_xor(i6,OFF), pi7=__shfl_xor(i7,OFF); \
    hc(v0,i0,pv7,pi7); hc(v1,i1,pv6,pi6); hc(v2,i2,pv5,pi5); hc(v3,i3,pv4,pi4); \
    hc(v4,i4,pv3,pi3); hc(v5,i5,pv2,pi2); hc(v6,i6,pv1,pi1); hc(v7,i7,pv0,pi0); \
    SORT8P(); } while (0)

// shared chunk-range computation (identical coverage in kernels A and B)
__device__ __forceinline__ void chunk_ranges(int r, int blk, int& c0, int& c1,
                                             int& al, int& vend) {
    c0 = blk * CHA;
    c1 = c0 + CHA; if (c1 > VOCAB) c1 = VOCAB;
    const size_t row_off = (size_t)r * VOCAB;
    const int a = (int)(row_off & 3);
    al = c0 + ((4 - ((a + c0) & 3)) & 3); if (al > c1) al = c1;
    vend = al + ((c1 - al) & ~3);
}

// ---------------------------------------------------------------------------
// Kernel A: per-thread raw max over its chunk (~1 VALU op/elem, pure stream),
// block-reduce to top-8 of thread-maxes (values only). Also zeroes counters.
// Guarantee: row's 8th-largest T8 >= M8 (8th-largest thread-max), since the
// top-8 thread-maxes are 8 distinct elements >= M8.
// ---------------------------------------------------------------------------
__global__ __launch_bounds__(BLK)
void rowmax_kernel(const float* __restrict__ lprobs, float* __restrict__ blk8,
                   int* __restrict__ counters)
{
    const int tid = threadIdx.x, bid = blockIdx.x;
    if (bid < NROWS && tid == 0) counters[bid] = 0;
    const int r = bid / NB, blk = bid % NB;
    const float* p = lprobs + (size_t)r * VOCAB;

    int c0, c1, al, vend;
    chunk_ranges(r, blk, c0, c1, al, vend);

    float m = -INFINITY;
    for (int v = c0 + tid; v < al; v += BLK) m = fmaxf(m, p[v]);
    for (int v = al + tid * 4; v < vend; v += BLK * 4) {
        const float4 f = *reinterpret_cast<const float4*>(p + v);
        m = fmaxf(m, fmaxf(fmaxf(f.x, f.y), fmaxf(f.z, f.w)));
    }
    for (int v = vend + tid; v < c1; v += BLK) m = fmaxf(m, p[v]);

    // wave top-8 of per-lane maxes (values only), xor butterfly
    float w0 = m, w1 = -INFINITY, w2 = -INFINITY, w3 = -INFINITY,
          w4 = -INFINITY, w5 = -INFINITY, w6 = -INFINITY, w7 = -INFINITY;
    XMERGEV(32); XMERGEV(16); XMERGEV(8); XMERGEV(4); XMERGEV(2); XMERGEV(1);

    __shared__ float sw[4][8];
    const int wave = tid >> 6, lane = tid & 63;
    if (lane == 0) {
        sw[wave][0]=w0; sw[wave][1]=w1; sw[wave][2]=w2; sw[wave][3]=w3;
        sw[wave][4]=w4; sw[wave][5]=w5; sw[wave][6]=w6; sw[wave][7]=w7;
    }
    __syncthreads();
    if (tid == 0) {
        #pragma unroll
        for (int w = 1; w < 4; ++w) {
            INSV(sw[w][0]); INSV(sw[w][1]); INSV(sw[w][2]); INSV(sw[w][3]);
            INSV(sw[w][4]); INSV(sw[w][5]); INSV(sw[w][6]); INSV(sw[w][7]);
        }
        float* o = blk8 + (size_t)bid * 8;
        o[0]=w0; o[1]=w1; o[2]=w2; o[3]=w3; o[4]=w4; o[5]=w5; o[6]=w6; o[7]=w7;
    }
}

// wave-compacted append of rare filter survivors
__device__ __forceinline__ void append(bool prd, float val, int fi, int row,
                                       int* __restrict__ counters,
                                       Cand* __restrict__ lists)
{
    unsigned long long mk = __ballot(prd ? 1 : 0);
    if (mk == 0) return;
    const int lane = threadIdx.x & 63;
    const int leader = __ffsll((unsigned long long)mk) - 1;
    int base = 0;
    if (lane == leader) base = atomicAdd(&counters[row], __popcll(mk));
    base = __shfl(base, leader);
    if (prd) {
        const int pos = base + __popcll(mk & ((1ull << lane) - 1ull));
        if (pos < CAP) { Cand c; c.v = val; c.i = fi; lists[(size_t)row * CAP + pos] = c; }
    }
}

// ---------------------------------------------------------------------------
// Kernel B: rebuild R8 per block from the row's 32 staged values, then stream
// the same chunk with a max4 >= R8 wave-vote fast path; append survivors.
// ---------------------------------------------------------------------------
__global__ __launch_bounds__(BLK)
void filter_kernel(const float* __restrict__ lprobs, const float* __restrict__ blk8,
                   int* __restrict__ counters, Cand* __restrict__ lists)
{
    const int tid = threadIdx.x, bid = blockIdx.x;
    const int r = bid / NB, blk = bid % NB;
    const float* p = lprobs + (size_t)r * VOCAB;
    const int fb = ((r & 7) >> 2) * VOCAB;   // j*VOCAB, j = s>>2

    // every wave redundantly reduces the 32 block-local top-8 values -> R8
    const int lane = tid & 63;
    float w0 = (lane < 32) ? blk8[(size_t)(r * NB + (lane >> 3)) * 8 + (lane & 7)]
                           : -INFINITY;
    float w1=-INFINITY,w2=-INFINITY,w3=-INFINITY,w4=-INFINITY,w5=-INFINITY,w6=-INFINITY,w7=-INFINITY;
    XMERGEV(32); XMERGEV(16); XMERGEV(8); XMERGEV(4); XMERGEV(2); XMERGEV(1);
    const float R8 = w7;   // all lanes hold the same sorted-8 after butterfly

    int c0, c1, al, vend;
    chunk_ranges(r, blk, c0, c1, al, vend);

    for (int v = c0 + tid; v < al; v += BLK) {
        const float x = p[v];
        append(x >= R8, x, fb + v, r, counters, lists);
    }
    for (int v = al + tid * 4; v < vend; v += BLK * 4) {
        const float4 f = *reinterpret_cast<const float4*>(p + v);
        const float mx = fmaxf(fmaxf(f.x, f.y), fmaxf(f.z, f.w));
        if (__any(mx >= R8)) {
            append(f.x >= R8, f.x, fb + v,     r, counters, lists);
            append(f.y >= R8, f.y, fb + v + 1, r, counters, lists);
            append(f.z >= R8, f.z, fb + v + 2, r, counters, lists);
            append(f.w >= R8, f.w, fb + v + 3, r, counters, lists);
        }
    }
    for (int v = vend + tid; v < c1; v += BLK) {
        const float x = p[v];
        append(x >= R8, x, fb + v, r, counters, lists);
    }
}

// ---------------------------------------------------------------------------
// Kernel C: per batch. Stage 1: exact tie-broken top-8 per row from its short
// candidate list (8 lanes/row, xor merge). Stage 2: sequential 4-group
// penalized top-2 select + all outputs (ints as float32 VALUES).
// ---------------------------------------------------------------------------
__global__ __launch_bounds__(64)
void select_kernel(const float* __restrict__ scores, const float* __restrict__ go,
                   const int* __restrict__ mask, const int* __restrict__ step_p,
                   const int* __restrict__ counters, const Cand* __restrict__ lists,
                   float* __restrict__ out)
{
    const int b = blockIdx.x, t = threadIdx.x;
    const int rg = t >> 3;                 // beam row s = 0..7 within batch
    const int lc = t & 7;
    const int row = b * BEAM + rg;
    const float maskf = mask[row] ? 1.0f : 0.0f;
    const float sc = scores[row * NSTEP + (step_p[0] - 1)];
    int n = counters[row]; if (n > CAP) n = CAP;

    float v0=-INFINITY,v1=-INFINITY,v2=-INFINITY,v3=-INFINITY,
          v4=-INFINITY,v5=-INFINITY,v6=-INFINITY,v7=-INFINITY;
    int   i0=INT_MAX,i1=INT_MAX,i2=INT_MAX,i3=INT_MAX,
          i4=INT_MAX,i5=INT_MAX,i6=INT_MAX,i7=INT_MAX;
    for (int k = lc; k < n; k += 8) {
        const Cand cd = lists[(size_t)row * CAP + k];
        INSP(fmaf(maskf, cd.v, sc), cd.i);     // monotone transform; ties by idx
    }
    XMERGEP(4); XMERGEP(2); XMERGEP(1);        // stays within the 8-lane group

    __shared__ float cv[BEAM][8];
    __shared__ int   ci[BEAM][8];
    if (lc == 0) {
        cv[rg][0]=v0; cv[rg][1]=v1; cv[rg][2]=v2; cv[rg][3]=v3;
        cv[rg][4]=v4; cv[rg][5]=v5; cv[rg][6]=v6; cv[rg][7]=v7;
        ci[rg][0]=i0; ci[rg][1]=i1; ci[rg][2]=i2; ci[rg][3]=i3;
        ci[rg][4]=i4; ci[rg][5]=i5; ci[rg][6]=i6; ci[rg][7]=i7;
    }
    __syncthreads();

    __shared__ float cval[NG][2];
    __shared__ int   ctok[NG][2];
    __shared__ int   cbeam[NG][2];
    for (int g = 0; g < NG; ++g) {
        float val = -INFINITY; int fi = INT_MAX;
        if (t < 16) {                      // h = row-half (j), c = candidate slot
            const int h = t >> 3, c = t & 7;
            const int s = g + h * NG;
            val = cv[s][c]; fi = ci[s][c];
            const int tok = fi - h * VOCAB;
            if (g > 0 && mask[b * BEAM + s]) {
                for (int gp = 0; gp < g; ++gp) {
                    const float pen = 0.5f * (1.0f + go[b * (NG * NG) + g * NG + gp]);
                    if (tok == ctok[gp][0]) val -= pen;   // DIVERSITY_STRENGTH=-0.5
                    if (tok == ctok[gp][1]) val -= pen;
                }
            }
        }
        float a0 = val, a1 = -INFINITY; int j0 = fi, j1 = INT_MAX;
        #pragma unroll
        for (int off = 32; off > 0; off >>= 1) {
            const float q0 = __shfl_down(a0, off), q1 = __shfl_down(a1, off);
            const int   k0 = __shfl_down(j0, off), k1 = __shfl_down(j1, off);
            merge2(a0, j0, a1, j1, q0, k0, q1, k1);
        }
        if (t == 0) {
            const int h0 = (j0 >= VOCAB) ? 1 : 0;
            const int h1 = (j1 >= VOCAB) ? 1 : 0;
            cval[g][0] = a0;              cval[g][1] = a1;
            ctok[g][0] = j0 - h0 * VOCAB; ctok[g][1] = j1 - h1 * VOCAB;
            cbeam[g][0] = h0 * NG + g;    cbeam[g][1] = h1 * NG + g;
        }
        __syncthreads();
    }

    float* out_scores = out;            // [0,512)
    float* out_idx    = out + 512;      // token ids as float32 values
    float* out_bms    = out + 1024;     // beam ids as float32 values
    float* out_go     = out + 1536;

    if (t < 8) {   // t = rank*4 + g -> layout [b, rank*G + g]
        const int rank = t >> 2, g = t & 3;
        out_scores[b * 8 + t] = cval[g][rank];
        out_idx[b * 8 + t]    = (float)ctok[g][rank];
        out_bms[b * 8 + t]    = (float)cbeam[g][rank];
    }
    if (t < 16) {  // t = g1*4 + g2
        const int g1 = t >> 2, g2 = t & 3;
        int ov = 0;
        #pragma unroll
        for (int jj = 0; jj < 2; ++jj) {
            const int m1 = mask[b * BEAM + jj * NG + g1];
            const int m2 = mask[b * BEAM + jj * NG + g2];
            if (m1 && m2 && ctok[g1][jj] == ctok[g2][jj]) ++ov;
        }
        out_go[b * (NG * NG) + t] = (go[b * (NG * NG) + t] + (float)ov) * 0.5f;
    }
}

extern "C" void kernel_launch(void* const* d_in, const int* in_sizes, int n_in,
                              void* d_out, int out_size, void* d_ws, size_t ws_size,
                              hipStream_t stream) {
    const float* lprobs = (const float*)d_in[0];
    const float* scores = (const float*)d_in[1];
    const float* go     = (const float*)d_in[2];
    const int*   mask   = (const int*)d_in[3];
    // d_in[4] original_batch_idxs == arange(bsz): identity, unused.
    const int*   step_p = (const int*)d_in[5];

    float* blk8     = (float*)d_ws;                         // 2048*8*4  = 64 KB
    int*   counters = (int*)((char*)d_ws + 65536);          // 512*4     =  2 KB
    Cand*  lists    = (Cand*)((char*)d_ws + 65536 + 2048);  // 512*1024*8 = 4 MB
    float* out      = (float*)d_out;

    rowmax_kernel<<<dim3(NBLKS), dim3(BLK), 0, stream>>>(lprobs, blk8, counters);
    filter_kernel<<<dim3(NBLKS), dim3(BLK), 0, stream>>>(lprobs, blk8, counters, lists);
    select_kernel<<<dim3(BSZ), dim3(64), 0, stream>>>(scores, go, mask, step_p,
                                                      counters, lists, out);
}

// Round 9
// 175.793 us; speedup vs baseline: 1.0704x; 1.0704x over previous
//
#include <hip/hip_runtime.h>
#include <limits.h>
#include <math.h>

// Problem constants (fixed by setup_inputs)
#define VOCAB 50257
#define BSZ 64
#define BEAM 8
#define NG 4
#define NSTEP 5
#define BLK 256
#define NB 4                               // blocks per beam-row
#define CHA ((VOCAB + NB - 1) / NB)        // 12565 elements per block
#define NROWS (BSZ * BEAM)                 // 512
#define NBLKS (NROWS * NB)                 // 2048
#define SLAB 64                            // per-(row,block) candidate capacity
#define T_STATIC 3.0f                      // static filter threshold (certified below)

struct Cand { float v; int i; };

// ---------------- (value, index) exact primitives ----------
__device__ __forceinline__ bool pref(float av, int ai, float bv, int bi) {
    return (av > bv) || (av == bv && ai < bi);   // lax.top_k tie-break
}
__device__ __forceinline__ void ce(float& a, int& ia, float& b, int& ib) {
    if (pref(b, ib, a, ia)) { float tv = a; int ti = ia; a = b; ia = ib; b = tv; ib = ti; }
}
__device__ __forceinline__ void hc(float& a, int& ia, float b, int ib) {
    if (pref(b, ib, a, ia)) { a = b; ia = ib; }
}
__device__ __forceinline__ void merge2(float& v0, int& i0, float& v1, int& i1,
                                       float bv0, int bi0, float bv1, int bi1) {
    if (pref(bv0, bi0, v0, i0)) {
        float nv1; int ni1;
        if (pref(v0, i0, bv1, bi1)) { nv1 = v0; ni1 = i0; } else { nv1 = bv1; ni1 = bi1; }
        v0 = bv0; i0 = bi0; v1 = nv1; i1 = ni1;
    } else if (pref(bv0, bi0, v1, i1)) {
        v1 = bv0; i1 = bi0;
    }
}
#define SORT8P() do { \
    ce(v0,i0,v4,i4); ce(v1,i1,v5,i5); ce(v2,i2,v6,i6); ce(v3,i3,v7,i7); \
    ce(v0,i0,v2,i2); ce(v1,i1,v3,i3); ce(v4,i4,v6,i6); ce(v5,i5,v7,i7); \
    ce(v0,i0,v1,i1); ce(v2,i2,v3,i3); ce(v4,i4,v5,i5); ce(v6,i6,v7,i7); } while (0)
#define INSP(T, FI) do { float _t = (T); int _f = (FI); \
    if (pref(_t, _f, v7, i7)) { v7 = _t; i7 = _f; \
        ce(v6,i6,v7,i7); ce(v5,i5,v6,i6); ce(v4,i4,v5,i5); ce(v3,i3,v4,i4); \
        ce(v2,i2,v3,i3); ce(v1,i1,v2,i2); ce(v0,i0,v1,i1); } } while (0)
#define XMERGEP(OFF) do { \
    float pv0=__shfl_xor(v0,OFF), pv1=__shfl_xor(v1,OFF), pv2=__shfl_xor(v2,OFF), pv3=__shfl_xor(v3,OFF); \
    float pv4=__shfl_xor(v4,OFF), pv5=__shfl_xor(v5,OFF), pv6=__shfl_xor(v6,OFF), pv7=__shfl_xor(v7,OFF); \
    int   pi0=__shfl_xor(i0,OFF), pi1=__shfl_xor(i1,OFF), pi2=__shfl_xor(i2,OFF), pi3=__shfl_xor(i3,OFF); \
    int   pi4=__shfl_xor(i4,OFF), pi5=__shfl_xor(i5,OFF), pi6=__shfl_xor(i6,OFF), pi7=__shfl_xor(i7,OFF); \
    hc(v0,i0,pv7,pi7); hc(v1,i1,pv6,pi6); hc(v2,i2,pv5,pi5); hc(v3,i3,pv4,pi4); \
    hc(v4,i4,pv3,pi3); hc(v5,i5,pv2,pi2); hc(v6,i6,pv1,pi1); hc(v7,i7,pv0,pi0); \
    SORT8P(); } while (0)

// ---------------------------------------------------------------------------
// Kernel A: SINGLE streaming pass. Append every element with raw lp >= T to a
// per-(row,block) slab via LDS-atomic wave compaction. Store the RAW count
// (certificate: row exact iff sum(counts) >= 8 and every count <= SLAB —
// then the whole top-8 of the row is in the slabs, since 8th-largest >= T).
// ---------------------------------------------------------------------------
__device__ __forceinline__ void lappend(bool prd, float val, int fi,
                                        int* s_cnt, Cand* __restrict__ slab)
{
    unsigned long long mk = __ballot(prd ? 1 : 0);
    if (mk == 0) return;
    const int lane = threadIdx.x & 63;
    const int leader = __ffsll((unsigned long long)mk) - 1;
    int base = 0;
    if (lane == leader) base = atomicAdd(s_cnt, __popcll(mk));
    base = __shfl(base, leader);
    if (prd) {
        const int pos = base + __popcll(mk & ((1ull << lane) - 1ull));
        if (pos < SLAB) { Cand c; c.v = val; c.i = fi; slab[pos] = c; }
    }
}

__global__ __launch_bounds__(BLK)
void pass_kernel(const float* __restrict__ lprobs, int* __restrict__ slabCnt,
                 Cand* __restrict__ slabs)
{
    const int tid = threadIdx.x, bid = blockIdx.x;
    const int r = bid / NB, blk = bid % NB;
    const float* p = lprobs + (size_t)r * VOCAB;
    const int fb = ((r & 7) >> 2) * VOCAB;   // j*VOCAB, j = (row-in-batch)>>2

    __shared__ int s_cnt;
    if (tid == 0) s_cnt = 0;
    __syncthreads();
    Cand* slab = slabs + (size_t)bid * SLAB;

    int c0 = blk * CHA;
    int c1 = c0 + CHA; if (c1 > VOCAB) c1 = VOCAB;
    const int a = (int)(((size_t)r * VOCAB) & 3);
    int al = c0 + ((4 - ((a + c0) & 3)) & 3); if (al > c1) al = c1;
    const int vend = al + ((c1 - al) & ~3);

    for (int v = c0 + tid; v < al; v += BLK) {
        const float x = p[v];
        lappend(x >= T_STATIC, x, fb + v, &s_cnt, slab);
    }
    for (int v = al + tid * 4; v < vend; v += BLK * 4) {
        const float4 f = *reinterpret_cast<const float4*>(p + v);
        const float mx = fmaxf(fmaxf(f.x, f.y), fmaxf(f.z, f.w));
        if (__any(mx >= T_STATIC)) {
            lappend(f.x >= T_STATIC, f.x, fb + v,     &s_cnt, slab);
            lappend(f.y >= T_STATIC, f.y, fb + v + 1, &s_cnt, slab);
            lappend(f.z >= T_STATIC, f.z, fb + v + 2, &s_cnt, slab);
            lappend(f.w >= T_STATIC, f.w, fb + v + 3, &s_cnt, slab);
        }
    }
    for (int v = vend + tid; v < c1; v += BLK) {
        const float x = p[v];
        lappend(x >= T_STATIC, x, fb + v, &s_cnt, slab);
    }

    __syncthreads();
    if (tid == 0) slabCnt[bid] = s_cnt;   // raw count (may exceed SLAB)
}

// ---------------------------------------------------------------------------
// Kernel B: per batch. Stage 1: exact tie-broken per-row top-8 from the slabs
// (8 lanes/row). Masked rows: analytic (all values == sc -> indices fb+0..7).
// Certificate failure: exact full-row rescan (correctness net, never taken).
// Stage 2: sequential 4-group penalized top-2 select + all outputs
// (ints written as float32 VALUES; harness compares d_out as float32).
// ---------------------------------------------------------------------------
__global__ __launch_bounds__(64)
void select_kernel(const float* __restrict__ lprobs, const float* __restrict__ scores,
                   const float* __restrict__ go, const int* __restrict__ mask,
                   const int* __restrict__ step_p, const int* __restrict__ slabCnt,
                   const Cand* __restrict__ slabs, float* __restrict__ out)
{
    const int b = blockIdx.x, t = threadIdx.x;
    const int rg = t >> 3;                 // beam row s = 0..7 within batch
    const int lc = t & 7;
    const int row = b * BEAM + rg;
    const float maskf = mask[row] ? 1.0f : 0.0f;
    const float sc = scores[row * NSTEP + (step_p[0] - 1)];
    const int fb = (rg >> 2) * VOCAB;      // j*VOCAB

    float v0=-INFINITY,v1=-INFINITY,v2=-INFINITY,v3=-INFINITY,
          v4=-INFINITY,v5=-INFINITY,v6=-INFINITY,v7=-INFINITY;
    int   i0=INT_MAX,i1=INT_MAX,i2=INT_MAX,i3=INT_MAX,
          i4=INT_MAX,i5=INT_MAX,i6=INT_MAX,i7=INT_MAX;

    if (maskf == 0.0f) {
        // masked row: every transformed value == sc; top-8 = lowest flat idx
        v0 = sc; i0 = fb + lc;
    } else {
        // certificate: all slabs within capacity AND >= 8 total survivors
        int total = 0; bool ok = true;
        #pragma unroll
        for (int k = 0; k < NB; ++k) {
            const int c = slabCnt[row * NB + k];
            total += c; if (c > SLAB) ok = false;
        }
        if (ok && total >= 8) {
            #pragma unroll
            for (int k = 0; k < NB; ++k) {
                const int n = slabCnt[row * NB + k];
                const Cand* slab = slabs + (size_t)(row * NB + k) * SLAB;
                for (int q = lc; q < n; q += 8) {
                    const Cand cd = slab[q];
                    INSP(cd.v + sc, cd.i);
                }
            }
        } else {
            // exact fallback: full-row rescan (never triggered for this input)
            const float* p = lprobs + (size_t)row * VOCAB;
            for (int v = lc; v < VOCAB; v += 8) INSP(p[v] + sc, fb + v);
        }
    }
    XMERGEP(4); XMERGEP(2); XMERGEP(1);    // merge the 8 lanes of this row-group

    __shared__ float cv[BEAM][8];
    __shared__ int   ci[BEAM][8];
    if (lc == 0) {
        cv[rg][0]=v0; cv[rg][1]=v1; cv[rg][2]=v2; cv[rg][3]=v3;
        cv[rg][4]=v4; cv[rg][5]=v5; cv[rg][6]=v6; cv[rg][7]=v7;
        ci[rg][0]=i0; ci[rg][1]=i1; ci[rg][2]=i2; ci[rg][3]=i3;
        ci[rg][4]=i4; ci[rg][5]=i5; ci[rg][6]=i6; ci[rg][7]=i7;
    }
    __syncthreads();

    __shared__ float cval[NG][2];
    __shared__ int   ctok[NG][2];
    __shared__ int   cbeam[NG][2];
    for (int g = 0; g < NG; ++g) {
        float val = -INFINITY; int fi = INT_MAX;
        if (t < 16) {                      // h = row-half (j), c = candidate slot
            const int h = t >> 3, c = t & 7;
            const int s = g + h * NG;
            val = cv[s][c]; fi = ci[s][c];
            const int tok = fi - h * VOCAB;
            if (g > 0 && mask[b * BEAM + s]) {
                for (int gp = 0; gp < g; ++gp) {
                    const float pen = 0.5f * (1.0f + go[b * (NG * NG) + g * NG + gp]);
                    if (tok == ctok[gp][0]) val -= pen;   // DIVERSITY_STRENGTH=-0.5
                    if (tok == ctok[gp][1]) val -= pen;
                }
            }
        }
        float a0 = val, a1 = -INFINITY; int j0 = fi, j1 = INT_MAX;
        #pragma unroll
        for (int off = 32; off > 0; off >>= 1) {
            const float q0 = __shfl_down(a0, off), q1 = __shfl_down(a1, off);
            const int   k0 = __shfl_down(j0, off), k1 = __shfl_down(j1, off);
            merge2(a0, j0, a1, j1, q0, k0, q1, k1);
        }
        if (t == 0) {
            const int h0 = (j0 >= VOCAB) ? 1 : 0;
            const int h1 = (j1 >= VOCAB) ? 1 : 0;
            cval[g][0] = a0;              cval[g][1] = a1;
            ctok[g][0] = j0 - h0 * VOCAB; ctok[g][1] = j1 - h1 * VOCAB;
            cbeam[g][0] = h0 * NG + g;    cbeam[g][1] = h1 * NG + g;
        }
        __syncthreads();
    }

    float* out_scores = out;            // [0,512)
    float* out_idx    = out + 512;      // token ids as float32 values
    float* out_bms    = out + 1024;     // beam ids as float32 values
    float* out_go     = out + 1536;

    if (t < 8) {   // t = rank*4 + g -> layout [b, rank*G + g]
        const int rank = t >> 2, g = t & 3;
        out_scores[b * 8 + t] = cval[g][rank];
        out_idx[b * 8 + t]    = (float)ctok[g][rank];
        out_bms[b * 8 + t]    = (float)cbeam[g][rank];
    }
    if (t < 16) {  // t = g1*4 + g2
        const int g1 = t >> 2, g2 = t & 3;
        int ov = 0;
        #pragma unroll
        for (int jj = 0; jj < 2; ++jj) {
            const int m1 = mask[b * BEAM + jj * NG + g1];
            const int m2 = mask[b * BEAM + jj * NG + g2];
            if (m1 && m2 && ctok[g1][jj] == ctok[g2][jj]) ++ov;
        }
        out_go[b * (NG * NG) + t] = (go[b * (NG * NG) + t] + (float)ov) * 0.5f;
    }
}

extern "C" void kernel_launch(void* const* d_in, const int* in_sizes, int n_in,
                              void* d_out, int out_size, void* d_ws, size_t ws_size,
                              hipStream_t stream) {
    const float* lprobs = (const float*)d_in[0];
    const float* scores = (const float*)d_in[1];
    const float* go     = (const float*)d_in[2];
    const int*   mask   = (const int*)d_in[3];
    // d_in[4] original_batch_idxs == arange(bsz): identity, unused.
    const int*   step_p = (const int*)d_in[5];

    int*  slabCnt = (int*)d_ws;                        // 2048*4B   =  8 KB
    Cand* slabs   = (Cand*)((char*)d_ws + 8192);       // 2048*64*8 =  1 MB
    float* out    = (float*)d_out;

    pass_kernel<<<dim3(NBLKS), dim3(BLK), 0, stream>>>(lprobs, slabCnt, slabs);
    select_kernel<<<dim3(BSZ), dim3(64), 0, stream>>>(lprobs, scores, go, mask,
                                                      step_p, slabCnt, slabs, out);
}